// Round 2
// baseline (125.469 us; speedup 1.0000x reference)
//
#include <hip/hip_runtime.h>

// HamiltonianEvolution collapsed form:
//   gate is constant over the FFT axis -> ifft(fft(x)*gate).real == x*gate
//   out[b,t,:,d] = q_left_n[:,d] (*) ( x[b,t,:,d] ) (*) ( gate[d]*conj(q_right_n[:,d]) )
// (gate folded into the right quaternion: hamilton is bilinear, gate is a
//  per-channel real scalar.)
// Memory-bound streaming: 64 MiB read + 64 MiB write.

constexpr int QD = 256;   // quat_dim
constexpr int DM = 1024;  // d_model
constexpr float EPS = 1e-8f;

// ---------- prologue: fold params into d_ws (8 KB) ----------
// ws layout: P[4][QD] (normalized left), Rg[4][QD] (gate * conj(normalized right))
__global__ void ham_params_kernel(const float* __restrict__ ql,
                                  const float* __restrict__ qr,
                                  const float* __restrict__ gate,
                                  float* __restrict__ ws) {
    const int d = threadIdx.x;                 // one block of 256
    const float l0 = ql[0*QD+d], l1 = ql[1*QD+d], l2 = ql[2*QD+d], l3 = ql[3*QD+d];
    const float r0 = qr[0*QD+d], r1 = qr[1*QD+d], r2 = qr[2*QD+d], r3 = qr[3*QD+d];
    const float g  = gate[d];
    const float il = rsqrtf(l0*l0 + l1*l1 + l2*l2 + l3*l3 + EPS);
    const float gr = g * rsqrtf(r0*r0 + r1*r1 + r2*r2 + r3*r3 + EPS);
    ws[0*QD+d] = l0*il;  ws[1*QD+d] = l1*il;
    ws[2*QD+d] = l2*il;  ws[3*QD+d] = l3*il;
    ws[4*QD+d] =  r0*gr; ws[5*QD+d] = -r1*gr;
    ws[6*QD+d] = -r2*gr; ws[7*QD+d] = -r3*gr;
}

// ---------- helpers ----------
__device__ __forceinline__ float2 ntload2(const float* p) {
    union { unsigned long long u; float2 f; } c;
    c.u = __builtin_nontemporal_load(reinterpret_cast<const unsigned long long*>(p));
    return c.f;
}
__device__ __forceinline__ void ntstore2(float* p, float a, float b) {
    union { unsigned long long u; float2 f; } c;
    c.f = make_float2(a, b);
    __builtin_nontemporal_store(c.u, reinterpret_cast<unsigned long long*>(p));
}

__device__ __forceinline__ void sandwich(
    float aw, float ax, float ay, float az,
    float pw, float px, float py, float pz,
    float rw, float rx, float ry, float rz,
    float& ow, float& ox, float& oy, float& oz)
{
    const float tw = aw*rw - ax*rx - ay*ry - az*rz;
    const float tx = aw*rx + ax*rw + ay*rz - az*ry;
    const float ty = aw*ry - ax*rz + ay*rw + az*rx;
    const float tz = aw*rz + ax*ry - ay*rx + az*rw;
    ow = pw*tw - px*tx - py*ty - pz*tz;
    ox = pw*tx + px*tw + py*tz - pz*ty;
    oy = pw*ty - px*tz + py*tw + pz*tx;
    oz = pw*tz + px*ty - py*tx + pz*tw;
}

// ---------- main: one thread = one (row, 2-channel pair), no loop ----------
__global__ __launch_bounds__(256, 8) void ham_evo_kernel(
    const float* __restrict__ x,
    const float* __restrict__ ws,
    float* __restrict__ out)
{
    const int i  = blockIdx.x * 256 + threadIdx.x;
    const int bt = i >> 7;                 // row (b*T + t)
    const int c2 = (i & 127) * 2;          // channel pair

    // folded params (cached: 8 KB working set, L1-hit after warmup)
    const float* pb = ws + c2;
    const float2 P0 = *reinterpret_cast<const float2*>(pb + 0*QD);
    const float2 P1 = *reinterpret_cast<const float2*>(pb + 1*QD);
    const float2 P2 = *reinterpret_cast<const float2*>(pb + 2*QD);
    const float2 P3 = *reinterpret_cast<const float2*>(pb + 3*QD);
    const float2 R0 = *reinterpret_cast<const float2*>(pb + 4*QD);
    const float2 R1 = *reinterpret_cast<const float2*>(pb + 5*QD);
    const float2 R2 = *reinterpret_cast<const float2*>(pb + 6*QD);
    const float2 R3 = *reinterpret_cast<const float2*>(pb + 7*QD);

    const size_t base = (size_t)bt * DM + c2;
    const float* xb = x + base;
    float*       ob = out + base;

    const float2 xw = ntload2(xb + 0*QD);
    const float2 xx = ntload2(xb + 1*QD);
    const float2 xy = ntload2(xb + 2*QD);
    const float2 xz = ntload2(xb + 3*QD);

    float ow0, ox0, oy0, oz0, ow1, ox1, oy1, oz1;
    sandwich(xw.x, xx.x, xy.x, xz.x,
             P0.x, P1.x, P2.x, P3.x,
             R0.x, R1.x, R2.x, R3.x,
             ow0, ox0, oy0, oz0);
    sandwich(xw.y, xx.y, xy.y, xz.y,
             P0.y, P1.y, P2.y, P3.y,
             R0.y, R1.y, R2.y, R3.y,
             ow1, ox1, oy1, oz1);

    ntstore2(ob + 0*QD, ow0, ow1);
    ntstore2(ob + 1*QD, ox0, ox1);
    ntstore2(ob + 2*QD, oy0, oy1);
    ntstore2(ob + 3*QD, oz0, oz1);
}

extern "C" void kernel_launch(void* const* d_in, const int* in_sizes, int n_in,
                              void* d_out, int out_size, void* d_ws, size_t ws_size,
                              hipStream_t stream) {
    const float* x    = (const float*)d_in[0];
    const float* ql   = (const float*)d_in[1];
    const float* qr   = (const float*)d_in[2];
    const float* gate = (const float*)d_in[3];
    float* out = (float*)d_out;
    float* ws  = (float*)d_ws;

    ham_params_kernel<<<1, QD, 0, stream>>>(ql, qr, gate, ws);

    const int n_bt = out_size / DM;            // B*T rows (16384)
    const int total = n_bt * (QD / 2);         // one thread per (row, channel-pair)
    const int grid = total / 256;              // exact: 8192 blocks
    ham_evo_kernel<<<grid, 256, 0, stream>>>(x, ws, out);
}

// Round 3
// 124.358 us; speedup vs baseline: 1.0089x; 1.0089x over previous
//
#include <hip/hip_runtime.h>

// HamiltonianEvolution collapsed form:
//   spectral_gate is constant along the FFT (time) axis, so
//   ifft(fft(x)*gate).real == x * gate  (exact up to FFT roundoff).
//   Whole op == per-channel quaternion sandwich:
//     out[b,t,:,d] = q_left_n[:,d] (*) x[b,t,:,d] (*) (gate[d]*conj(q_right_n[:,d]))
//   (hamilton is bilinear; the real per-channel gate folds into the right factor.)
// Pure streaming: 64 MiB read + 64 MiB write -> floor ~20.3 us @ 6.3 TB/s.
// Single kernel: per-thread param fold for its own 2 channels (params are 2.25 KB
// total, broadcast L2-hits; ~25 VALU + 4 rsqrt per thread, hidden under the stream).

constexpr int QD = 256;   // quat_dim
constexpr int DM = 1024;  // d_model
constexpr float EPS = 1e-8f;

__device__ __forceinline__ float2 ntload2(const float* p) {
    union { unsigned long long u; float2 f; } c;
    c.u = __builtin_nontemporal_load(reinterpret_cast<const unsigned long long*>(p));
    return c.f;
}
__device__ __forceinline__ void ntstore2(float* p, float a, float b) {
    union { unsigned long long u; float2 f; } c;
    c.f = make_float2(a, b);
    __builtin_nontemporal_store(c.u, reinterpret_cast<unsigned long long*>(p));
}

__device__ __forceinline__ void sandwich(
    float aw, float ax, float ay, float az,
    float pw, float px, float py, float pz,
    float rw, float rx, float ry, float rz,
    float& ow, float& ox, float& oy, float& oz)
{
    // t = a (*) rconj
    const float tw = aw*rw - ax*rx - ay*ry - az*rz;
    const float tx = aw*rx + ax*rw + ay*rz - az*ry;
    const float ty = aw*ry - ax*rz + ay*rw + az*rx;
    const float tz = aw*rz + ax*ry - ay*rx + az*rw;
    // o = p (*) t
    ow = pw*tw - px*tx - py*ty - pz*tz;
    ox = pw*tx + px*tw + py*tz - pz*ty;
    oy = pw*ty - px*tz + py*tw + pz*tx;
    oz = pw*tz + px*ty - py*tx + pz*tw;
}

__global__ __launch_bounds__(256, 8) void ham_evo_kernel(
    const float* __restrict__ x,
    const float* __restrict__ ql,
    const float* __restrict__ qr,
    const float* __restrict__ gate,
    float* __restrict__ out)
{
    const int i  = blockIdx.x * 256 + threadIdx.x;
    const int bt = i >> 7;                 // row (b*T + t)
    const int c2 = (i & 127) * 2;          // this thread's channel pair

    // ---- fold params for channels c2, c2+1 (tiny broadcast reads, cache-hot) ----
    const float2 L0 = *reinterpret_cast<const float2*>(ql + 0*QD + c2);
    const float2 L1 = *reinterpret_cast<const float2*>(ql + 1*QD + c2);
    const float2 L2 = *reinterpret_cast<const float2*>(ql + 2*QD + c2);
    const float2 L3 = *reinterpret_cast<const float2*>(ql + 3*QD + c2);
    const float2 R0 = *reinterpret_cast<const float2*>(qr + 0*QD + c2);
    const float2 R1 = *reinterpret_cast<const float2*>(qr + 1*QD + c2);
    const float2 R2 = *reinterpret_cast<const float2*>(qr + 2*QD + c2);
    const float2 R3 = *reinterpret_cast<const float2*>(qr + 3*QD + c2);
    const float2 G  = *reinterpret_cast<const float2*>(gate + c2);

    // channel 0
    const float il0 = rsqrtf(L0.x*L0.x + L1.x*L1.x + L2.x*L2.x + L3.x*L3.x + EPS);
    const float pw0 = L0.x*il0, px0 = L1.x*il0, py0 = L2.x*il0, pz0 = L3.x*il0;
    const float gr0 = G.x * rsqrtf(R0.x*R0.x + R1.x*R1.x + R2.x*R2.x + R3.x*R3.x + EPS);
    const float rw0 = R0.x*gr0, rx0 = -R1.x*gr0, ry0 = -R2.x*gr0, rz0 = -R3.x*gr0;
    // channel 1
    const float il1 = rsqrtf(L0.y*L0.y + L1.y*L1.y + L2.y*L2.y + L3.y*L3.y + EPS);
    const float pw1 = L0.y*il1, px1 = L1.y*il1, py1 = L2.y*il1, pz1 = L3.y*il1;
    const float gr1 = G.y * rsqrtf(R0.y*R0.y + R1.y*R1.y + R2.y*R2.y + R3.y*R3.y + EPS);
    const float rw1 = R0.y*gr1, rx1 = -R1.y*gr1, ry1 = -R2.y*gr1, rz1 = -R3.y*gr1;

    // ---- stream one row-pair-slice: 64 B in, 64 B out ----
    const size_t base = (size_t)bt * DM + c2;
    const float* xb = x + base;
    float*       ob = out + base;

    const float2 xw = ntload2(xb + 0*QD);
    const float2 xx = ntload2(xb + 1*QD);
    const float2 xy = ntload2(xb + 2*QD);
    const float2 xz = ntload2(xb + 3*QD);

    float ow0, ox0, oy0, oz0, ow1, ox1, oy1, oz1;
    sandwich(xw.x, xx.x, xy.x, xz.x, pw0, px0, py0, pz0, rw0, rx0, ry0, rz0,
             ow0, ox0, oy0, oz0);
    sandwich(xw.y, xx.y, xy.y, xz.y, pw1, px1, py1, pz1, rw1, rx1, ry1, rz1,
             ow1, ox1, oy1, oz1);

    ntstore2(ob + 0*QD, ow0, ow1);
    ntstore2(ob + 1*QD, ox0, ox1);
    ntstore2(ob + 2*QD, oy0, oy1);
    ntstore2(ob + 3*QD, oz0, oz1);
}

extern "C" void kernel_launch(void* const* d_in, const int* in_sizes, int n_in,
                              void* d_out, int out_size, void* d_ws, size_t ws_size,
                              hipStream_t stream) {
    const float* x    = (const float*)d_in[0];
    const float* ql   = (const float*)d_in[1];
    const float* qr   = (const float*)d_in[2];
    const float* gate = (const float*)d_in[3];
    float* out = (float*)d_out;

    const int n_bt  = out_size / DM;          // B*T rows (16384)
    const int total = n_bt * (QD / 2);        // one thread per (row, channel-pair)
    const int grid  = total / 256;            // exact: 8192 blocks
    ham_evo_kernel<<<grid, 256, 0, stream>>>(x, ql, qr, gate, out);
}